// Round 10
// baseline (1513.963 us; speedup 1.0000x reference)
//
#include <hip/hip_runtime.h>
#include <math.h>

// B=32, C=D=64, H=W=64, K=1024
constexpr int K_CODES = 1024;
constexpr int D_DIM   = 64;
constexpr int HW      = 4096;
constexpr int NPOS    = 131072;
constexpr int CHW     = 262144;
constexpr int NTILE   = K_CODES / 16;   // 64 N-tiles of 16 codes

typedef short bf16x8 __attribute__((ext_vector_type(8)));
typedef float f32x4  __attribute__((ext_vector_type(4)));

__device__ __forceinline__ unsigned short f2bf(float f) {
    unsigned u = __float_as_uint(f);
    return (unsigned short)((u + 0x7FFFu + ((u >> 16) & 1u)) >> 16);
}
// monotone float->uint map (order-preserving incl. negatives)
__device__ __forceinline__ unsigned mapf(float f) {
    unsigned u = __float_as_uint(f);
    return u ^ ((unsigned)((int)u >> 31) | 0x80000000u);
}
__device__ __forceinline__ float unmapf(unsigned v) {
    unsigned u = (v & 0x80000000u) ? (v & 0x7FFFFFFFu) : ~v;
    return __uint_as_float(u);
}
__device__ __forceinline__ unsigned long long umin64(unsigned long long a,
                                                     unsigned long long b) {
    return a < b ? a : b;
}

// ws layout: [0..1023] c2 fp32 | [1024..2047] histogram fp32 |
//            byte 8192.. : codebook bf16 [1024][64] (128 KB)
__global__ void vq_prep(const float* __restrict__ cb, float* __restrict__ ws) {
    int k = blockIdx.x * blockDim.x + threadIdx.x;
    if (k < K_CODES) {
        const float4* row = reinterpret_cast<const float4*>(cb + k * D_DIM);
        float s0 = 0.f, s1 = 0.f, s2 = 0.f, s3 = 0.f;
#pragma unroll
        for (int i = 0; i < 16; ++i) {
            float4 v = row[i];
            s0 = fmaf(v.x, v.x, s0);
            s1 = fmaf(v.y, v.y, s1);
            s2 = fmaf(v.z, v.z, s2);
            s3 = fmaf(v.w, v.w, s3);
        }
        ws[k] = (s0 + s1) + (s2 + s3);
        ws[K_CODES + k] = 0.0f;
        unsigned short* cbh = (unsigned short*)(ws + 2048);
#pragma unroll
        for (int d = 0; d < D_DIM; ++d) cbh[k * D_DIM + d] = f2bf(cb[k * D_DIM + d]);
    }
}

// r9 was correct (absmax 0.0) but 6.3e7 LDS-atomic bank conflicts: 16 lanes
// per wave hammered the same msl/win address. This version: per-lane running
// u64 (mapped-dist,idx) min in REGISTERS + width-16 shfl_xor butterfly
// (value-identical to atomicMin incl. first-index ties). No LDS atomics.
// x_lds stride 65 (conflict-free), exact verify reads x/c2 from global.
#define FOR_R(M) M(0) M(1) M(2) M(3)

__global__ __launch_bounds__(256)
__attribute__((amdgpu_waves_per_eu(1, 6)))
void vq_main(const float* __restrict__ in, const float* __restrict__ cb,
             float* __restrict__ out, float* __restrict__ ws) {
    float* hist = ws + K_CODES;
    const float* __restrict__ c2g = ws;
    const unsigned short* cbh = (const unsigned short*)(ws + 2048);

    __shared__ float x_lds[64][65];          // stride 65: bank = (row+col)%32
    __shared__ float x2_lds[64];
    __shared__ unsigned long long win[64];

    const int t   = threadIdx.x;
    const int l   = t & 63;
    const int w   = t >> 6;
    const int nbase = blockIdx.x * 64;       // 64 positions, same batch b
    const int b   = nbase >> 12;
    const int hw0 = nbase & 4095;
    const float* xb = in + (size_t)b * CHW + hw0;

    // stage x: thread (l,w) loads 16 channels for position l (coalesced)
#pragma unroll
    for (int cc = 0; cc < 16; ++cc) {
        int c = w * 16 + cc;
        x_lds[l][c] = xb[(size_t)c * HW + l];
    }
    __syncthreads();

    // x2 in the exact 4-partial order (bit-identical to rounds 1-9)
    if (t < 64) {
        float s0 = 0.f, s1 = 0.f, s2 = 0.f, s3 = 0.f;
#pragma unroll
        for (int i = 0; i < 16; ++i) {
            s0 = fmaf(x_lds[t][4 * i + 0], x_lds[t][4 * i + 0], s0);
            s1 = fmaf(x_lds[t][4 * i + 1], x_lds[t][4 * i + 1], s1);
            s2 = fmaf(x_lds[t][4 * i + 2], x_lds[t][4 * i + 2], s2);
            s3 = fmaf(x_lds[t][4 * i + 3], x_lds[t][4 * i + 3], s3);
        }
        x2_lds[t] = (s0 + s1) + (s2 + s3);
    }
    __syncthreads();

    const int nlo = l & 15;   // A-row / B-col / D-col (code within tile)
    const int kq  = l >> 4;   // k-quarter

    // A fragments: A[m=nlo][k=kq*8+j (+32)] for this wave's 16 positions
    bf16x8 a0, a1;
#pragma unroll
    for (int j = 0; j < 8; ++j) {
        a0[j] = (short)f2bf(x_lds[w * 16 + nlo][kq * 8 + j]);
        a1[j] = (short)f2bf(x_lds[w * 16 + nlo][kq * 8 + 32 + j]);
    }
    // D rows this lane owns: position prow_r = w*16 + kq*4 + r
    const int prow0 = w * 16 + kq * 4 + 0, prow1 = prow0 + 1;
    const int prow2 = prow0 + 2,           prow3 = prow0 + 3;
    const float x2r0 = x2_lds[prow0], x2r1 = x2_lds[prow1];
    const float x2r2 = x2_lds[prow2], x2r3 = x2_lds[prow3];

    // ---- Phase A: approx distances, per-lane running min, shfl reduce ----
    unsigned long long m0 = ~0ull, m1 = ~0ull, m2 = ~0ull, m3 = ~0ull;
    for (int tile = 0; tile < NTILE; ++tile) {
        const unsigned short* bp = cbh + (tile * 16 + nlo) * D_DIM + kq * 8;
        bf16x8 b0 = *(const bf16x8*)(bp);
        bf16x8 b1 = *(const bf16x8*)(bp + 32);
        f32x4 acc = {0.f, 0.f, 0.f, 0.f};
        acc = __builtin_amdgcn_mfma_f32_16x16x32_bf16(a0, b0, acc, 0, 0, 0);
        acc = __builtin_amdgcn_mfma_f32_16x16x32_bf16(a1, b1, acc, 0, 0, 0);
        const float c2n = c2g[tile * 16 + nlo];
        const unsigned code = (unsigned)(tile * 16 + nlo);
#define UPD(r) { \
        float dt = fmaf(-2.0f, acc[r], x2r##r) + c2n; \
        unsigned long long pk = ((unsigned long long)mapf(dt) << 32) | code; \
        m##r = umin64(m##r, pk); }
        FOR_R(UPD)
#undef UPD
    }
#define REDA(r) { \
    m##r = umin64(m##r, __shfl_xor(m##r, 1, 16)); \
    m##r = umin64(m##r, __shfl_xor(m##r, 2, 16)); \
    m##r = umin64(m##r, __shfl_xor(m##r, 4, 16)); \
    m##r = umin64(m##r, __shfl_xor(m##r, 8, 16)); }
    FOR_R(REDA)
#undef REDA
    // candidate thresholds (same sound margin that gave absmax 0.0 in r9)
    const float thr0 = unmapf((unsigned)(m0 >> 32)) + (0.02f * sqrtf(x2r0) + 0.02f);
    const float thr1 = unmapf((unsigned)(m1 >> 32)) + (0.02f * sqrtf(x2r1) + 0.02f);
    const float thr2 = unmapf((unsigned)(m2 >> 32)) + (0.02f * sqrtf(x2r2) + 0.02f);
    const float thr3 = unmapf((unsigned)(m3 >> 32)) + (0.02f * sqrtf(x2r3) + 0.02f);

    // ---- Phase B: exact fp32 verify of candidates (registers + shfl) ----
    unsigned long long w0 = ~0ull, w1 = ~0ull, w2 = ~0ull, w3 = ~0ull;
    for (int tile = 0; tile < NTILE; ++tile) {
        const unsigned short* bp = cbh + (tile * 16 + nlo) * D_DIM + kq * 8;
        bf16x8 b0 = *(const bf16x8*)(bp);
        bf16x8 b1 = *(const bf16x8*)(bp + 32);
        f32x4 acc = {0.f, 0.f, 0.f, 0.f};
        acc = __builtin_amdgcn_mfma_f32_16x16x32_bf16(a0, b0, acc, 0, 0, 0);
        acc = __builtin_amdgcn_mfma_f32_16x16x32_bf16(a1, b1, acc, 0, 0, 0);
        const float c2n = c2g[tile * 16 + nlo];
        const int   n   = tile * 16 + nlo;
        const float4* cr = (const float4*)(cb + n * D_DIM);
#define VER(r) { \
        float dt = fmaf(-2.0f, acc[r], x2r##r) + c2n; \
        if (dt <= thr##r) { \
            const float* xg = in + (size_t)b * CHW + hw0 + prow##r; \
            float d0 = 0.f, d1 = 0.f, d2 = 0.f, d3 = 0.f; \
            _Pragma("unroll") \
            for (int i = 0; i < 16; ++i) { \
                float4 v = cr[i]; \
                d0 = fmaf(xg[(size_t)(4 * i + 0) * HW], v.x, d0); \
                d1 = fmaf(xg[(size_t)(4 * i + 1) * HW], v.y, d1); \
                d2 = fmaf(xg[(size_t)(4 * i + 2) * HW], v.z, d2); \
                d3 = fmaf(xg[(size_t)(4 * i + 3) * HW], v.w, d3); } \
            float dot  = (d0 + d1) + (d2 + d3); \
            float dist = (x2r##r - 2.0f * dot) + c2n; \
            unsigned long long pk = \
                ((unsigned long long)mapf(dist) << 32) | (unsigned)n; \
            w##r = umin64(w##r, pk); } }
        FOR_R(VER)
#undef VER
    }
#define REDB(r) { \
    w##r = umin64(w##r, __shfl_xor(w##r, 1, 16)); \
    w##r = umin64(w##r, __shfl_xor(w##r, 2, 16)); \
    w##r = umin64(w##r, __shfl_xor(w##r, 4, 16)); \
    w##r = umin64(w##r, __shfl_xor(w##r, 8, 16)); }
    FOR_R(REDB)
#undef REDB
    if (nlo == 0) {
        win[prow0] = w0; win[prow1] = w1; win[prow2] = w2; win[prow3] = w3;
    }
    __syncthreads();

    // ---- finale: gather + straight-through output + histogram ----
    const int fidx = (int)(win[l] & 0xFFFFFFFFu);
    float* ob = out + (size_t)b * CHW + hw0;
    const float* qr = cb + fidx * D_DIM;
#pragma unroll
    for (int cc = 0; cc < 16; ++cc) {
        int c = w * 16 + cc;
        float x = x_lds[l][c];
        float q = qr[c];
        ob[(size_t)c * HW + l] = x + (q - x);
    }
    if (t < 64) atomicAdd(&hist[fidx], 1.0f);
}

// perplexity: one block, 1024 threads (16 waves)
__global__ void vq_ppl(const float* __restrict__ ws, float* __restrict__ outp) {
    __shared__ float red[16];
    int t = threadIdx.x;
    float e = ws[K_CODES + t] * (1.0f / (float)NPOS);
    float term = e * logf(e + 1e-10f);
#pragma unroll
    for (int off = 32; off > 0; off >>= 1)
        term += __shfl_down(term, off, 64);
    int lane = t & 63, wid = t >> 6;
    if (lane == 0) red[wid] = term;
    __syncthreads();
    if (t == 0) {
        float s = 0.f;
#pragma unroll
        for (int i = 0; i < 16; ++i) s += red[i];
        *outp = expf(-s);
    }
}

extern "C" void kernel_launch(void* const* d_in, const int* in_sizes, int n_in,
                              void* d_out, int out_size, void* d_ws, size_t ws_size,
                              hipStream_t stream) {
    const float* in = (const float*)d_in[0];   // [32,64,64,64] fp32
    const float* cb = (const float*)d_in[1];   // [1024,64] fp32
    float* out = (float*)d_out;                // quantized [8388608] + ppl [1]
    float* ws  = (float*)d_ws;                 // 8 KB + 128 KB bf16 codebook

    vq_prep<<<4, 256, 0, stream>>>(cb, ws);
    vq_main<<<NPOS / 64, 256, 0, stream>>>(in, cb, out, ws);
    vq_ppl<<<1, 1024, 0, stream>>>(ws, out + (size_t)8388608);
}

// Round 11
// 437.984 us; speedup vs baseline: 3.4567x; 3.4567x over previous
//
#include <hip/hip_runtime.h>
#include <math.h>

// B=32, C=D=64, H=W=64, K=1024
constexpr int K_CODES = 1024;
constexpr int D_DIM   = 64;
constexpr int HW      = 4096;
constexpr int NPOS    = 131072;
constexpr int CHW     = 262144;
constexpr int NTILE   = K_CODES / 16;   // 64 tiles of 16 codes

typedef short bf16x8 __attribute__((ext_vector_type(8)));
typedef float f32x4  __attribute__((ext_vector_type(4)));

__device__ __forceinline__ unsigned short f2bf(float f) {
    unsigned u = __float_as_uint(f);
    return (unsigned short)((u + 0x7FFFu + ((u >> 16) & 1u)) >> 16);
}
__device__ __forceinline__ unsigned mapf(float f) {
    unsigned u = __float_as_uint(f);
    return u ^ ((unsigned)((int)u >> 31) | 0x80000000u);
}
__device__ __forceinline__ unsigned long long umin64(unsigned long long a,
                                                     unsigned long long b) {
    return a < b ? a : b;
}

// ws layout: [0..1023] c2 fp32 | [1024..2047] histogram fp32 |
//            byte 8192.. : codebook bf16 [1024][64] (128 KB)
__global__ void vq_prep(const float* __restrict__ cb, float* __restrict__ ws) {
    int k = blockIdx.x * blockDim.x + threadIdx.x;
    if (k < K_CODES) {
        const float4* row = reinterpret_cast<const float4*>(cb + k * D_DIM);
        float s0 = 0.f, s1 = 0.f, s2 = 0.f, s3 = 0.f;
#pragma unroll
        for (int i = 0; i < 16; ++i) {
            float4 v = row[i];
            s0 = fmaf(v.x, v.x, s0);
            s1 = fmaf(v.y, v.y, s1);
            s2 = fmaf(v.z, v.z, s2);
            s3 = fmaf(v.w, v.w, s3);
        }
        ws[k] = (s0 + s1) + (s2 + s3);
        ws[K_CODES + k] = 0.0f;
        unsigned short* cbh = (unsigned short*)(ws + 2048);
#pragma unroll
        for (int d = 0; d < D_DIM; ++d) cbh[k * D_DIM + d] = f2bf(cb[k * D_DIM + d]);
    }
}

// r9: correct but LDS-atomic-bound (6.3e7 conflicts). r10: register reduce
// but global-strided verify spilled (VGPR 256, 450MB scratch). r11 = r9's
// LDS-sourced verify + r10's register/shfl reduce + float-only Phase A min.
#define FOR_R(M) M(0) M(1) M(2) M(3)

__global__ __launch_bounds__(256)
__attribute__((amdgpu_waves_per_eu(1, 4)))
void vq_main(const float* __restrict__ in, const float* __restrict__ cb,
             float* __restrict__ out, float* __restrict__ ws) {
    float* hist = ws + K_CODES;
    const unsigned short* cbh = (const unsigned short*)(ws + 2048);

    __shared__ float x_lds[64][65];      // stride 65: (l + c) % 32 banks
    __shared__ float x2_lds[64];
    __shared__ float c2s[K_CODES];
    __shared__ unsigned long long win[64];

    const int t   = threadIdx.x;
    const int l   = t & 63;
    const int w   = t >> 6;
    const int nbase = blockIdx.x * 64;
    const int b   = nbase >> 12;
    const int hw0 = nbase & 4095;
    const float* xb = in + (size_t)b * CHW + hw0;

    // stage x (coalesced) + c2 into LDS
#pragma unroll
    for (int cc = 0; cc < 16; ++cc) {
        int c = w * 16 + cc;
        x_lds[l][c] = xb[(size_t)c * HW + l];
    }
#pragma unroll
    for (int j = 0; j < 4; ++j) c2s[t + j * 256] = ws[t + j * 256];
    __syncthreads();

    // x2 in the exact 4-partial order (bit-identical to rounds 1-10)
    if (t < 64) {
        float s0 = 0.f, s1 = 0.f, s2 = 0.f, s3 = 0.f;
#pragma unroll
        for (int i = 0; i < 16; ++i) {
            s0 = fmaf(x_lds[t][4 * i + 0], x_lds[t][4 * i + 0], s0);
            s1 = fmaf(x_lds[t][4 * i + 1], x_lds[t][4 * i + 1], s1);
            s2 = fmaf(x_lds[t][4 * i + 2], x_lds[t][4 * i + 2], s2);
            s3 = fmaf(x_lds[t][4 * i + 3], x_lds[t][4 * i + 3], s3);
        }
        x2_lds[t] = (s0 + s1) + (s2 + s3);
    }
    __syncthreads();

    const int nlo = l & 15;   // code within tile (A-row / B-col / D-col)
    const int kq  = l >> 4;   // k-quarter

    // A fragments for this wave's 16 positions
    bf16x8 a0, a1;
#pragma unroll
    for (int j = 0; j < 8; ++j) {
        a0[j] = (short)f2bf(x_lds[w * 16 + nlo][kq * 8 + j]);
        a1[j] = (short)f2bf(x_lds[w * 16 + nlo][kq * 8 + 32 + j]);
    }
    // D rows this lane owns: position prow_r = w*16 + kq*4 + r
    const int prow0 = w * 16 + kq * 4, prow1 = prow0 + 1;
    const int prow2 = prow0 + 2,       prow3 = prow0 + 3;

    // ---- Phase A: float-min of score = c2 - 2*dot (x2 constant per pos) ----
    float fm0 = INFINITY, fm1 = INFINITY, fm2 = INFINITY, fm3 = INFINITY;
#pragma unroll 2
    for (int tile = 0; tile < NTILE; ++tile) {
        const unsigned short* bp = cbh + (tile * 16 + nlo) * D_DIM + kq * 8;
        bf16x8 b0 = *(const bf16x8*)(bp);
        bf16x8 b1 = *(const bf16x8*)(bp + 32);
        f32x4 acc = {0.f, 0.f, 0.f, 0.f};
        acc = __builtin_amdgcn_mfma_f32_16x16x32_bf16(a0, b0, acc, 0, 0, 0);
        acc = __builtin_amdgcn_mfma_f32_16x16x32_bf16(a1, b1, acc, 0, 0, 0);
        const float c2n = c2s[tile * 16 + nlo];
#define UPD(r) { float sc = fmaf(-2.0f, acc[r], c2n); fm##r = fminf(fm##r, sc); }
        FOR_R(UPD)
#undef UPD
    }
#define REDA(r) { \
    fm##r = fminf(fm##r, __shfl_xor(fm##r, 1, 16)); \
    fm##r = fminf(fm##r, __shfl_xor(fm##r, 2, 16)); \
    fm##r = fminf(fm##r, __shfl_xor(fm##r, 4, 16)); \
    fm##r = fminf(fm##r, __shfl_xor(fm##r, 8, 16)); }
    FOR_R(REDA)
#undef REDA

    const float x2r0 = x2_lds[prow0], x2r1 = x2_lds[prow1];
    const float x2r2 = x2_lds[prow2], x2r3 = x2_lds[prow3];
    // candidate thresholds: same sound margin that passed bitwise in r9
    const float thr0 = fm0 + (0.02f * sqrtf(x2r0) + 0.02f);
    const float thr1 = fm1 + (0.02f * sqrtf(x2r1) + 0.02f);
    const float thr2 = fm2 + (0.02f * sqrtf(x2r2) + 0.02f);
    const float thr3 = fm3 + (0.02f * sqrtf(x2r3) + 0.02f);

    // ---- Phase B: rescan; exact fp32 verify of candidates (x from LDS) ----
    unsigned long long w0 = ~0ull, w1 = ~0ull, w2 = ~0ull, w3 = ~0ull;
#pragma unroll 1
    for (int tile = 0; tile < NTILE; ++tile) {
        const unsigned short* bp = cbh + (tile * 16 + nlo) * D_DIM + kq * 8;
        bf16x8 b0 = *(const bf16x8*)(bp);
        bf16x8 b1 = *(const bf16x8*)(bp + 32);
        f32x4 acc = {0.f, 0.f, 0.f, 0.f};
        acc = __builtin_amdgcn_mfma_f32_16x16x32_bf16(a0, b0, acc, 0, 0, 0);
        acc = __builtin_amdgcn_mfma_f32_16x16x32_bf16(a1, b1, acc, 0, 0, 0);
        const float c2n = c2s[tile * 16 + nlo];
        const int   n   = tile * 16 + nlo;
#define VER(r) { \
        float sc = fmaf(-2.0f, acc[r], c2n); \
        if (sc <= thr##r) { \
            const float* xr = &x_lds[prow##r][0];   /* broadcast in group */ \
            const float4* cr = (const float4*)(cb + n * D_DIM); \
            float d0 = 0.f, d1 = 0.f, d2 = 0.f, d3 = 0.f; \
            _Pragma("unroll") \
            for (int i = 0; i < 16; ++i) { \
                float4 v = cr[i]; \
                d0 = fmaf(xr[4 * i + 0], v.x, d0); \
                d1 = fmaf(xr[4 * i + 1], v.y, d1); \
                d2 = fmaf(xr[4 * i + 2], v.z, d2); \
                d3 = fmaf(xr[4 * i + 3], v.w, d3); } \
            float dot  = (d0 + d1) + (d2 + d3); \
            float dist = (x2r##r - 2.0f * dot) + c2n; \
            unsigned long long pk = \
                ((unsigned long long)mapf(dist) << 32) | (unsigned)n; \
            w##r = umin64(w##r, pk); } }
        FOR_R(VER)
#undef VER
    }
#define REDB(r) { \
    w##r = umin64(w##r, __shfl_xor(w##r, 1, 16)); \
    w##r = umin64(w##r, __shfl_xor(w##r, 2, 16)); \
    w##r = umin64(w##r, __shfl_xor(w##r, 4, 16)); \
    w##r = umin64(w##r, __shfl_xor(w##r, 8, 16)); }
    FOR_R(REDB)
#undef REDB
    if (nlo == 0) {
        win[prow0] = w0; win[prow1] = w1; win[prow2] = w2; win[prow3] = w3;
    }
    __syncthreads();

    // ---- finale: gather + straight-through output + histogram ----
    const int fidx = (int)(win[l] & 0xFFFFFFFFu);
    float* ob = out + (size_t)b * CHW + hw0;
    const float* qr = cb + fidx * D_DIM;
#pragma unroll
    for (int cc = 0; cc < 16; ++cc) {
        int c = w * 16 + cc;
        float x = x_lds[l][c];
        float q = qr[c];
        ob[(size_t)c * HW + l] = x + (q - x);
    }
    if (t < 64) atomicAdd(&hist[fidx], 1.0f);
}

// perplexity: one block, 1024 threads (16 waves)
__global__ void vq_ppl(const float* __restrict__ ws, float* __restrict__ outp) {
    __shared__ float red[16];
    int t = threadIdx.x;
    float e = ws[K_CODES + t] * (1.0f / (float)NPOS);
    float term = e * logf(e + 1e-10f);
#pragma unroll
    for (int off = 32; off > 0; off >>= 1)
        term += __shfl_down(term, off, 64);
    int lane = t & 63, wid = t >> 6;
    if (lane == 0) red[wid] = term;
    __syncthreads();
    if (t == 0) {
        float s = 0.f;
#pragma unroll
        for (int i = 0; i < 16; ++i) s += red[i];
        *outp = expf(-s);
    }
}

extern "C" void kernel_launch(void* const* d_in, const int* in_sizes, int n_in,
                              void* d_out, int out_size, void* d_ws, size_t ws_size,
                              hipStream_t stream) {
    const float* in = (const float*)d_in[0];   // [32,64,64,64] fp32
    const float* cb = (const float*)d_in[1];   // [1024,64] fp32
    float* out = (float*)d_out;                // quantized [8388608] + ppl [1]
    float* ws  = (float*)d_ws;                 // 8 KB + 128 KB bf16 codebook

    vq_prep<<<4, 256, 0, stream>>>(cb, ws);
    vq_main<<<NPOS / 64, 256, 0, stream>>>(in, cb, out, ws);
    vq_ppl<<<1, 1024, 0, stream>>>(ws, out + (size_t)8388608);
}